// Round 7
// baseline (761.267 us; speedup 1.0000x reference)
//
#include <hip/hip_runtime.h>
#include <hip/hip_bf16.h>
#include <math.h>

// Problem constants
constexpr int BB   = 8;
constexpr int NN   = 4096;
constexpr int MM   = 1024;
constexpr int KK   = 16;
constexpr int COUT = 128;
constexpr int NWRK = 992;    // worker waves: (256-8) blocks * 4 waves
#define RSQ 0.09f

typedef float f32x2 __attribute__((ext_vector_type(2)));

__device__ __forceinline__ float dist2_exact(float ax, float ay, float az,
                                             float bx, float by, float bz) {
    // (a-b)^2 summed, no fma contraction: match numpy mul-then-add semantics
    float dx = __fsub_rn(ax, bx);
    float dy = __fsub_rn(ay, by);
    float dz = __fsub_rn(az, bz);
    return __fadd_rn(__fadd_rn(__fmul_rn(dx, dx), __fmul_rn(dy, dy)), __fmul_rn(dz, dz));
}

template<int CTRL>
__device__ __forceinline__ unsigned dpp_mov_u(unsigned v) {
    return (unsigned)__builtin_amdgcn_update_dpp((int)v, (int)v, CTRL, 0xF, 0xF, false);
}
// DPP mov with row_mask: masked-off rows keep old (=v) -> safe identity for max/min
template<int CTRL, int RMASK>
__device__ __forceinline__ unsigned dpp_mov_rm(unsigned v) {
    return (unsigned)__builtin_amdgcn_update_dpp((int)v, (int)v, CTRL, RMASK, 0xF, false);
}
__device__ __forceinline__ float readlane_f(float v, int j) {
    return __int_as_float(__builtin_amdgcn_readlane(__float_as_int(v), j));
}
__device__ __forceinline__ unsigned umax2(unsigned a, unsigned b) { return a > b ? a : b; }
__device__ __forceinline__ unsigned long long umax64(unsigned long long a, unsigned long long b) {
    return a > b ? a : b;
}
// max3-shaped nesting: clang fuses fmaxf(fmaxf(a,b),c) -> v_max3_f32
__device__ __forceinline__ float m3(float a, float b, float c) {
    return fmaxf(fmaxf(a, b), c);
}

// ---------------------------------------------------------------------------
// FUSED producer-consumer kernel.
//
// r24 -> r25 post-mortem: r24 WON (744 -> 689us dispatch): ballot tie-break
// (-80cyc chain) + float2 dist update. Remaining dominant reducible block is
// the post-barrier serial chain: keys-read(130) -> merge(25) -> DEPENDENT
// spos[fi] read(130). Changes:
//  * SPECULATIVE own-candidate coord fetch: post-barrier, each wave issues
//    spos[g_mine] IN PARALLEL with the key reads (latencies overlap). With
//    p=1/4 the winner is the own candidate (fi==g_mine, wave-uniform
//    branch) and the dependent second read is skipped. E ~ -30 cyc/iter.
//    Issued AFTER the barrier -> cannot extend the pre-barrier lgkm drain.
//    Keep-alive asm pin stops the compiler sinking the load into the branch.
//  * reduce tree re-nested in max3 shape (15 fmax -> 8 v_max3_f32 if clang
//    fuses; identical otherwise -> downside-free).
//  * batch publish moved to wave 1 (wave 0 already does shist+slot writes);
//    shist cross-wave visibility guaranteed by the intervening barrier.
// ---------------------------------------------------------------------------
__global__ __launch_bounds__(256, 1) void fused_kernel(const float* __restrict__ x,
                                                       const float* __restrict__ pos,
                                                       const float* __restrict__ W1,
                                                       const float* __restrict__ b1,
                                                       const float* __restrict__ W2,
                                                       const float* __restrict__ b2,
                                                       const float* __restrict__ W3,
                                                       const float* __restrict__ b3,
                                                       unsigned* __restrict__ gsel,
                                                       float* __restrict__ out,
                                                       float* __restrict__ pos_s,
                                                       float* __restrict__ batch_s) {
    // producer LDS
    __shared__ float4 spos[NN];                       // 64 KB
    __shared__ int    shist[MM];                      // 4 KB
    __shared__ __align__(16) unsigned long long slotK[2][4];
    // consumer LDS
    __shared__ float sW2[64 * 64];                    // 16 KB
    __shared__ float sW3[64 * 128];                   // 32 KB
    __shared__ int   nslot[4][16];

    const int tid  = threadIdx.x;
    const int lane = tid & 63;
    const int wave = tid >> 6;

    if (blockIdx.x < BB) {
        // =================== PRODUCER: FPS ===================
        const int b = blockIdx.x;
        const float* pb = pos + (size_t)b * NN * 3;

        for (int i = tid; i < NN; i += 256)
            spos[i] = make_float4(pb[i * 3 + 0], pb[i * 3 + 1], pb[i * 3 + 2], 0.0f);
        for (int i = tid; i < MM; i += 256)
            batch_s[(size_t)b * MM + i] = (float)b;
        if (tid == 0) {
            shist[0] = 0;
            __hip_atomic_store(&gsel[(size_t)b * MM], 1u, __ATOMIC_RELAXED,
                               __HIP_MEMORY_SCOPE_AGENT);   // m=0 -> point 0
        }
        if (tid < 8) slotK[tid >> 2][tid & 3] = 0ull;
        __syncthreads();

        // CONTIGUOUS ownership: thread t owns points g = 16t + k (k=0..15),
        // pair-packed: pair p holds k=2p (lane .x) and k=2p+1 (lane .y).
        // One-time bank-conflicted staging reads (~2us) — off the loop.
        f32x2 px2[8], py2[8], pz2[8], d2[8];
        const float4 p0 = spos[0];
#pragma unroll
        for (int p = 0; p < 8; p++) {
            float4 a = spos[tid * 16 + 2 * p];
            float4 c = spos[tid * 16 + 2 * p + 1];
            px2[p][0] = a.x; px2[p][1] = c.x;
            py2[p][0] = a.y; py2[p][1] = c.y;
            pz2[p][0] = a.z; pz2[p][1] = c.z;
            d2[p][0] = dist2_exact(a.x, a.y, a.z, p0.x, p0.y, p0.z);
            d2[p][1] = dist2_exact(c.x, c.y, c.z, p0.x, p0.y, p0.z);
        }
        float bv;
        {
            // max3-shaped tree over 16 values: 5 inner m3 (15 vals) + 2 m3 + 1
            float q0 = m3(d2[0][0], d2[0][1], d2[1][0]);
            float q1 = m3(d2[1][1], d2[2][0], d2[2][1]);
            float q2 = m3(d2[3][0], d2[3][1], d2[4][0]);
            float q3 = m3(d2[4][1], d2[5][0], d2[5][1]);
            float q4 = m3(d2[6][0], d2[6][1], d2[7][0]);
            bv = fmaxf(m3(q0, q1, q2), m3(q3, q4, d2[7][1]));
        }

        for (int m = 1; m < MM; m++) {
            const int par = m & 1;
            const unsigned tagm = (unsigned)m;

            const unsigned bvb = __float_as_uint(bv);

            // full-wave max via DPP: shr 1,2,4,8 then row_bcast15/31; lane63
            unsigned rv = bvb;
            rv = umax2(rv, dpp_mov_u<0x111>(rv));
            rv = umax2(rv, dpp_mov_u<0x112>(rv));
            rv = umax2(rv, dpp_mov_u<0x114>(rv));
            rv = umax2(rv, dpp_mov_u<0x118>(rv));
            rv = umax2(rv, dpp_mov_rm<0x142, 0xa>(rv));   // lane15->16..31, 47->48..63
            rv = umax2(rv, dpp_mov_rm<0x143, 0xc>(rv));   // lane31->32..63
            const unsigned vstar = (unsigned)__builtin_amdgcn_readlane((int)rv, 63);

            // per-thread first-match k (min k = min g within thread)
            unsigned kmask = 0u;
#pragma unroll
            for (int p = 0; p < 8; p++) {
                kmask |= (d2[p][0] == bv) ? (1u << (2 * p)) : 0u;
                kmask |= (d2[p][1] == bv) ? (1u << (2 * p + 1)) : 0u;
            }
            const int kstar = __builtin_ctz(kmask);

            // wave-min global index among value-ties: lowest participating
            // lane (g monotone in lane) + its kstar.
            const unsigned long long ball = __ballot(bvb == vstar);
            const int L  = (int)__builtin_ctzll(ball);
            const int kL = __builtin_amdgcn_readlane(kstar, L);
            const unsigned g = ((unsigned)(wave * 64 + L) << 4) | (unsigned)kL;

            if (lane == 0) {
                slotK[par][wave] =
                    ((unsigned long long)vstar << 32)
                    | (unsigned long long)(((4095u - g) << 10) | tagm);
            }
            __syncthreads();   // slot visibility; parity buffer protects one-ahead

            // post-barrier: keys read and OWN-candidate coord read issued
            // back-to-back -> latencies overlap.
            const ulonglong2 ka = *(const ulonglong2*)&slotK[par][0];
            const ulonglong2 kb = *(const ulonglong2*)&slotK[par][2];
            float4 spec = spos[g];             // speculative: own candidate
            // pin: stop the compiler sinking this load into the taken branch
            asm volatile("" : "+v"(spec.x), "+v"(spec.y), "+v"(spec.z));

            const unsigned long long kA = umax64(ka.x, ka.y);
            const unsigned long long kB = umax64(kb.x, kb.y);
            const unsigned long long kk = umax64(kA, kB);
            const int fi = 4095 - (int)(((unsigned)kk >> 10) & 4095u);

            float4 sp;
            if (fi == (int)g) {                // wave-uniform branch
                sp = spec;                     // hit (p=1/4): skip second read
            } else {
                sp = spos[fi];                 // miss: dependent read as before
            }

            if (tid == 0) shist[m] = fi;       // LDS only; published in batches
            // batched publish on WAVE 1 (wave 0 already does shist+slot
            // writes). shist[base..base+7] all written before the iter-m
            // barrier -> visible cross-wave here.
            if (((m & 7) == 1) && m > 1 && wave == 1 && lane < 8) {
                const int base = m - 8;
                __hip_atomic_store(&gsel[(size_t)b * MM + base + lane],
                                   (unsigned)(shist[base + lane] + 1),
                                   __ATOMIC_RELAXED, __HIP_MEMORY_SCOPE_AGENT);
            }

            if (m < MM - 1) {
#pragma clang fp contract(off)
                const f32x2 sx = { sp.x, sp.x };
                const f32x2 sy = { sp.y, sp.y };
                const f32x2 sz = { sp.z, sp.z };
#pragma unroll
                for (int p = 0; p < 8; p++) {
                    f32x2 dx = px2[p] - sx;               // IEEE sub
                    f32x2 dy = py2[p] - sy;
                    f32x2 dz = pz2[p] - sz;
                    f32x2 tt = dx * dx + dy * dy + dz * dz;  // ((xx+yy)+zz), no fma
                    d2[p][0] = fminf(d2[p][0], tt[0]);
                    d2[p][1] = fminf(d2[p][1], tt[1]);
                }
                float q0 = m3(d2[0][0], d2[0][1], d2[1][0]);
                float q1 = m3(d2[1][1], d2[2][0], d2[2][1]);
                float q2 = m3(d2[3][0], d2[3][1], d2[4][0]);
                float q3 = m3(d2[4][1], d2[5][0], d2[5][1]);
                float q4 = m3(d2[6][0], d2[6][1], d2[7][0]);
                bv = fmaxf(m3(q0, q1, q2), m3(q3, q4, d2[7][1]));
            }
        }

        __syncthreads();
        // tail publish: m=1017..1023 (last in-loop batch covered through 1016)
        if (tid < 7) {
            const int mm = 1017 + tid;
            __hip_atomic_store(&gsel[(size_t)b * MM + mm],
                               (unsigned)(shist[mm] + 1),
                               __ATOMIC_RELAXED, __HIP_MEMORY_SCOPE_AGENT);
        }
        for (int i = tid; i < MM; i += 256) {
            float4 sp = spos[shist[i]];
            size_t o = (size_t)b * MM + i;
            pos_s[o * 3 + 0] = sp.x;
            pos_s[o * 3 + 1] = sp.y;
            pos_s[o * 3 + 2] = sp.z;
        }
        return;
    }

    // ===================== CONSUMER: radius + MLP =====================
    {
        const float4* s2 = (const float4*)W2;
        float4*       d2 = (float4*)sW2;
        for (int i = tid; i < 64 * 64 / 4; i += 256) d2[i] = s2[i];
        const float4* s3 = (const float4*)W3;
        float4*       d3 = (float4*)sW3;
        for (int i = tid; i < 64 * 128 / 4; i += 256) d3[i] = s3[i];
    }
    float w1c[6];
#pragma unroll
    for (int c = 0; c < 6; c++) w1c[c] = W1[c * 64 + lane];
    const float bb1  = b1[lane];
    const float bb2  = b2[lane];
    const float bb3a = b3[lane];
    const float bb3b = b3[64 + lane];
    __syncthreads();

    const int W = (blockIdx.x - BB) * 4 + wave;    // 0..991

    // collect this wave's queries and sort by m = q & 1023 (availability order)
    int myq[9]; int nq = 0;
#pragma unroll
    for (int k = 0; k < 9; k++) {
        int q = W + NWRK * k;
        if (q < BB * MM) myq[nq++] = q;
    }
    for (int i = 1; i < nq; i++) {                 // insertion sort (<=9 elems)
        int v = myq[i]; int j = i - 1;
        while (j >= 0 && (myq[j] & 1023) > (v & 1023)) { myq[j + 1] = myq[j]; j--; }
        myq[j + 1] = v;
    }

    for (int i = 0; i < nq; i++) {
        const int q = myq[i];

        // ---- wait for this single query (one address, deep sleep) ----
        unsigned v = 0u;
        int guard = 0;
        for (;;) {
            v = __hip_atomic_load(&gsel[q], __ATOMIC_RELAXED,
                                  __HIP_MEMORY_SCOPE_AGENT);
            if (v >= 1u && v <= (unsigned)NN) break;
            if (++guard > 6000) break;             // ~20ms bound: fail loudly
            __builtin_amdgcn_s_sleep(127);         // ~8128 cyc =~ 3.4us idle
        }
        if (v == 0u || v > (unsigned)NN) continue;

        // ---------- process query q ----------
        const int b  = q >> 10;
        const int fi = (int)v - 1;
        const float qx = pos[((size_t)b * NN + fi) * 3 + 0];
        const float qy = pos[((size_t)b * NN + fi) * 3 + 1];
        const float qz = pos[((size_t)b * NN + fi) * 3 + 2];

        // radius scan: first-16 by index within RSQ (identical semantics)
        if (lane < 16) nslot[wave][lane] = 0;
        const float* pb = pos + (size_t)b * NN * 3;
        int cnt = 0;
        for (int c = 0; c < NN / 64; c++) {
            int p = c * 64 + lane;
            float px = pb[p * 3 + 0], py = pb[p * 3 + 1], pz = pb[p * 3 + 2];
            float d2 = dist2_exact(qx, qy, qz, px, py, pz);
            bool val = (d2 <= RSQ);
            unsigned long long msk = __ballot(val);
            if (val) {
                int rank = __popcll(msk & ((1ull << lane) - 1ull));
                int slot = cnt + rank;
                if (slot < KK) nslot[wave][slot] = p;
            }
            cnt += __popcll(msk);
            if (cnt >= KK) break;
        }
        const int cnt16 = min(cnt, KK);

        const int4 n0 = *(const int4*)&nslot[wave][0];
        const int4 n1 = *(const int4*)&nslot[wave][4];
        const int4 n2 = *(const int4*)&nslot[wave][8];
        const int4 n3 = *(const int4*)&nslot[wave][12];
        const int nidx[16] = { n0.x, n0.y, n0.z, n0.w, n1.x, n1.y, n1.z, n1.w,
                               n2.x, n2.y, n2.z, n2.w, n3.x, n3.y, n3.z, n3.w };

        // layer 1
        float h[17];
        unsigned vmask = 1u << 16;
#pragma unroll
        for (int e = 0; e < 16; e++) {
            const int p = (e < cnt16) ? nidx[e] : 0;
            const int g = b * NN + p;
            if ((e < cnt16) && (g != q)) vmask |= (1u << e);
            const float f0 = x[(size_t)g * 3 + 0];
            const float f1 = x[(size_t)g * 3 + 1];
            const float f2 = x[(size_t)g * 3 + 2];
            const float f3 = pos[(size_t)g * 3 + 0] - qx;
            const float f4 = pos[(size_t)g * 3 + 1] - qy;
            const float f5 = pos[(size_t)g * 3 + 2] - qz;
            float t = bb1 + f0 * w1c[0] + f1 * w1c[1] + f2 * w1c[2]
                          + f3 * w1c[3] + f4 * w1c[4] + f5 * w1c[5];
            h[e] = fmaxf(t, 0.0f);
        }
        {   // added self-loop (PyG numeric quirk)
            const int g = q;
            const float f0 = x[(size_t)g * 3 + 0];
            const float f1 = x[(size_t)g * 3 + 1];
            const float f2 = x[(size_t)g * 3 + 2];
            const float f3 = pos[(size_t)g * 3 + 0] - qx;
            const float f4 = pos[(size_t)g * 3 + 1] - qy;
            const float f5 = pos[(size_t)g * 3 + 2] - qz;
            float t = bb1 + f0 * w1c[0] + f1 * w1c[1] + f2 * w1c[2]
                          + f3 * w1c[3] + f4 * w1c[4] + f5 * w1c[5];
            h[16] = fmaxf(t, 0.0f);
        }

        // layer 2
        float acc[17];
#pragma unroll
        for (int e = 0; e < 17; e++) acc[e] = bb2;
#pragma unroll 2
        for (int j = 0; j < 64; j++) {
            const float wj = sW2[j * 64 + lane];
#pragma unroll
            for (int e = 0; e < 17; e++) {
                const float hj = readlane_f(h[e], j);
                acc[e] = __builtin_fmaf(hj, wj, acc[e]);
            }
        }
#pragma unroll
        for (int e = 0; e < 17; e++) h[e] = fmaxf(acc[e], 0.0f);

        // layer 3
        float a0[17], a1[17];
#pragma unroll
        for (int e = 0; e < 17; e++) { a0[e] = bb3a; a1[e] = bb3b; }
#pragma unroll 2
        for (int j = 0; j < 64; j++) {
            const float wa = sW3[j * 128 + lane];
            const float wb = sW3[j * 128 + 64 + lane];
#pragma unroll
            for (int e = 0; e < 17; e++) {
                const float hj = readlane_f(h[e], j);
                a0[e] = __builtin_fmaf(hj, wa, a0[e]);
                a1[e] = __builtin_fmaf(hj, wb, a1[e]);
            }
        }

        // masked max
        float m0 = -INFINITY, m1 = -INFINITY;
#pragma unroll
        for (int e = 0; e < 17; e++) {
            const bool vv = (vmask >> e) & 1u;
            m0 = vv ? fmaxf(m0, a0[e]) : m0;
            m1 = vv ? fmaxf(m1, a1[e]) : m1;
        }
        out[(size_t)q * COUT + lane]      = m0;
        out[(size_t)q * COUT + 64 + lane] = m1;
    }
}

// ---------------------------------------------------------------------------
extern "C" void kernel_launch(void* const* d_in, const int* in_sizes, int n_in,
                              void* d_out, int out_size, void* d_ws, size_t ws_size,
                              hipStream_t stream) {
    const float* x   = (const float*)d_in[0];
    const float* pos = (const float*)d_in[1];
    // d_in[2] = batch (unused: layout is implicit)
    const float* W1 = (const float*)d_in[3];
    const float* b1 = (const float*)d_in[4];
    const float* W2 = (const float*)d_in[5];
    const float* b2 = (const float*)d_in[6];
    const float* W3 = (const float*)d_in[7];
    const float* b3 = (const float*)d_in[8];

    float* outF    = (float*)d_out;
    float* out     = outF;                                  // [B*M, 128]
    float* pos_s   = outF + (size_t)BB * MM * COUT;         // [B*M, 3]
    float* batch_s = pos_s + (size_t)BB * MM * 3;           // [B*M]

    unsigned* gsel = (unsigned*)d_ws;                       // [B*M] selection index+1

    hipMemsetAsync(gsel, 0, (size_t)BB * MM * sizeof(unsigned), stream);

    fused_kernel<<<256, 256, 0, stream>>>(x, pos, W1, b1, W2, b2, W3, b3,
                                          gsel, out, pos_s, batch_s);
}

// Round 8
// 745.104 us; speedup vs baseline: 1.0217x; 1.0217x over previous
//
#include <hip/hip_runtime.h>
#include <hip/hip_bf16.h>
#include <math.h>

// Problem constants
constexpr int BB   = 8;
constexpr int NN   = 4096;
constexpr int MM   = 1024;
constexpr int KK   = 16;
constexpr int COUT = 128;
constexpr int NWRK = 992;    // worker waves: (256-8) blocks * 4 waves
#define RSQ 0.09f

typedef float f32x2 __attribute__((ext_vector_type(2)));

__device__ __forceinline__ float dist2_exact(float ax, float ay, float az,
                                             float bx, float by, float bz) {
    // (a-b)^2 summed, no fma contraction: match numpy mul-then-add semantics
    float dx = __fsub_rn(ax, bx);
    float dy = __fsub_rn(ay, by);
    float dz = __fsub_rn(az, bz);
    return __fadd_rn(__fadd_rn(__fmul_rn(dx, dx), __fmul_rn(dy, dy)), __fmul_rn(dz, dz));
}

template<int CTRL>
__device__ __forceinline__ unsigned dpp_mov_u(unsigned v) {
    return (unsigned)__builtin_amdgcn_update_dpp((int)v, (int)v, CTRL, 0xF, 0xF, false);
}
// DPP mov with row_mask: masked-off rows keep old (=v) -> safe identity for max/min
template<int CTRL, int RMASK>
__device__ __forceinline__ unsigned dpp_mov_rm(unsigned v) {
    return (unsigned)__builtin_amdgcn_update_dpp((int)v, (int)v, CTRL, RMASK, 0xF, false);
}
__device__ __forceinline__ float readlane_f(float v, int j) {
    return __int_as_float(__builtin_amdgcn_readlane(__float_as_int(v), j));
}
__device__ __forceinline__ unsigned umax2(unsigned a, unsigned b) { return a > b ? a : b; }
__device__ __forceinline__ unsigned long long umax64(unsigned long long a, unsigned long long b) {
    return a > b ? a : b;
}
// max3-shaped nesting: clang fuses fmaxf(fmaxf(a,b),c) -> v_max3_f32
__device__ __forceinline__ float m3(float a, float b, float c) {
    return fmaxf(fmaxf(a, b), c);
}

// ---------------------------------------------------------------------------
// FUSED producer-consumer kernel.
//
// r25 -> r26 post-mortem: r25 (spec-fetch + max3 + wave1-publish) regressed
// 689 -> 703us. The speculative own-candidate fetch ADDS a guaranteed
// ds_read + lgkm wait + branch to every iteration for a p=1/4 saving whose
// hit-path still waits on the same drain — net negative. Reverted to r24's
// exchange verbatim (lane0 slot write, tid<8 publish, plain spos[fi] read).
// KEPT only max3: the bv reduce tree in v_max3 shape (15 fmax -> 8 ops,
// pure serial-path instruction removal, zero added latency risk).
// DVFS note: VALUBusy 16%, HBM 0.14% -> chip likely down-clocked; remaining
// upside is chain links removed, not instructions shaved.
// ---------------------------------------------------------------------------
__global__ __launch_bounds__(256, 1) void fused_kernel(const float* __restrict__ x,
                                                       const float* __restrict__ pos,
                                                       const float* __restrict__ W1,
                                                       const float* __restrict__ b1,
                                                       const float* __restrict__ W2,
                                                       const float* __restrict__ b2,
                                                       const float* __restrict__ W3,
                                                       const float* __restrict__ b3,
                                                       unsigned* __restrict__ gsel,
                                                       float* __restrict__ out,
                                                       float* __restrict__ pos_s,
                                                       float* __restrict__ batch_s) {
    // producer LDS
    __shared__ float4 spos[NN];                       // 64 KB
    __shared__ int    shist[MM];                      // 4 KB
    __shared__ __align__(16) unsigned long long slotK[2][4];
    // consumer LDS
    __shared__ float sW2[64 * 64];                    // 16 KB
    __shared__ float sW3[64 * 128];                   // 32 KB
    __shared__ int   nslot[4][16];

    const int tid  = threadIdx.x;
    const int lane = tid & 63;
    const int wave = tid >> 6;

    if (blockIdx.x < BB) {
        // =================== PRODUCER: FPS ===================
        const int b = blockIdx.x;
        const float* pb = pos + (size_t)b * NN * 3;

        for (int i = tid; i < NN; i += 256)
            spos[i] = make_float4(pb[i * 3 + 0], pb[i * 3 + 1], pb[i * 3 + 2], 0.0f);
        for (int i = tid; i < MM; i += 256)
            batch_s[(size_t)b * MM + i] = (float)b;
        if (tid == 0) {
            shist[0] = 0;
            __hip_atomic_store(&gsel[(size_t)b * MM], 1u, __ATOMIC_RELAXED,
                               __HIP_MEMORY_SCOPE_AGENT);   // m=0 -> point 0
        }
        if (tid < 8) slotK[tid >> 2][tid & 3] = 0ull;
        __syncthreads();

        // CONTIGUOUS ownership: thread t owns points g = 16t + k (k=0..15),
        // pair-packed: pair p holds k=2p (lane .x) and k=2p+1 (lane .y).
        // One-time bank-conflicted staging reads (~2us) — off the loop.
        f32x2 px2[8], py2[8], pz2[8], d2[8];
        const float4 p0 = spos[0];
#pragma unroll
        for (int p = 0; p < 8; p++) {
            float4 a = spos[tid * 16 + 2 * p];
            float4 c = spos[tid * 16 + 2 * p + 1];
            px2[p][0] = a.x; px2[p][1] = c.x;
            py2[p][0] = a.y; py2[p][1] = c.y;
            pz2[p][0] = a.z; pz2[p][1] = c.z;
            d2[p][0] = dist2_exact(a.x, a.y, a.z, p0.x, p0.y, p0.z);
            d2[p][1] = dist2_exact(c.x, c.y, c.z, p0.x, p0.y, p0.z);
        }
        float bv;
        {
            // max3-shaped tree over 16 values: 5 inner m3 + 2 m3 + 1 fmax
            float q0 = m3(d2[0][0], d2[0][1], d2[1][0]);
            float q1 = m3(d2[1][1], d2[2][0], d2[2][1]);
            float q2 = m3(d2[3][0], d2[3][1], d2[4][0]);
            float q3 = m3(d2[4][1], d2[5][0], d2[5][1]);
            float q4 = m3(d2[6][0], d2[6][1], d2[7][0]);
            bv = fmaxf(m3(q0, q1, q2), m3(q3, q4, d2[7][1]));
        }

        for (int m = 1; m < MM; m++) {
            const int par = m & 1;
            const unsigned tagm = (unsigned)m;

            const unsigned bvb = __float_as_uint(bv);

            // full-wave max via DPP: shr 1,2,4,8 then row_bcast15/31; lane63
            unsigned rv = bvb;
            rv = umax2(rv, dpp_mov_u<0x111>(rv));
            rv = umax2(rv, dpp_mov_u<0x112>(rv));
            rv = umax2(rv, dpp_mov_u<0x114>(rv));
            rv = umax2(rv, dpp_mov_u<0x118>(rv));
            rv = umax2(rv, dpp_mov_rm<0x142, 0xa>(rv));   // lane15->16..31, 47->48..63
            rv = umax2(rv, dpp_mov_rm<0x143, 0xc>(rv));   // lane31->32..63
            const unsigned vstar = (unsigned)__builtin_amdgcn_readlane((int)rv, 63);

            // per-thread first-match k (min k = min g within thread)
            unsigned kmask = 0u;
#pragma unroll
            for (int p = 0; p < 8; p++) {
                kmask |= (d2[p][0] == bv) ? (1u << (2 * p)) : 0u;
                kmask |= (d2[p][1] == bv) ? (1u << (2 * p + 1)) : 0u;
            }
            const int kstar = __builtin_ctz(kmask);

            // wave-min global index among value-ties: lowest participating
            // lane (g monotone in lane) + its kstar.
            const unsigned long long ball = __ballot(bvb == vstar);
            const int L  = (int)__builtin_ctzll(ball);
            const int kL = __builtin_amdgcn_readlane(kstar, L);
            const unsigned g = ((unsigned)(wave * 64 + L) << 4) | (unsigned)kL;

            if (lane == 0) {
                slotK[par][wave] =
                    ((unsigned long long)vstar << 32)
                    | (unsigned long long)(((4095u - g) << 10) | tagm);
            }
            __syncthreads();   // slot visibility; parity buffer protects one-ahead

            const ulonglong2 ka = *(const ulonglong2*)&slotK[par][0];
            const ulonglong2 kb = *(const ulonglong2*)&slotK[par][2];
            const unsigned long long kA = umax64(ka.x, ka.y);
            const unsigned long long kB = umax64(kb.x, kb.y);
            const unsigned long long kk = umax64(kA, kB);
            const int fi = 4095 - (int)(((unsigned)kk >> 10) & 4095u);

            const float4 sp = spos[fi];        // issue LDS read early

            if (tid == 0) shist[m] = fi;       // LDS only; published in batches
            // batched publish: selections m-8..m-1 (shist written/read by wave
            // 0 only -> same-wave LDS ordering). Issued just after the
            // barrier: store ack never delays a barrier.
            if (((m & 7) == 1) && m > 1 && tid < 8) {
                const int base = m - 8;
                __hip_atomic_store(&gsel[(size_t)b * MM + base + tid],
                                   (unsigned)(shist[base + tid] + 1),
                                   __ATOMIC_RELAXED, __HIP_MEMORY_SCOPE_AGENT);
            }

            if (m < MM - 1) {
#pragma clang fp contract(off)
                const f32x2 sx = { sp.x, sp.x };
                const f32x2 sy = { sp.y, sp.y };
                const f32x2 sz = { sp.z, sp.z };
#pragma unroll
                for (int p = 0; p < 8; p++) {
                    f32x2 dx = px2[p] - sx;               // IEEE sub
                    f32x2 dy = py2[p] - sy;
                    f32x2 dz = pz2[p] - sz;
                    f32x2 tt = dx * dx + dy * dy + dz * dz;  // ((xx+yy)+zz), no fma
                    d2[p][0] = fminf(d2[p][0], tt[0]);
                    d2[p][1] = fminf(d2[p][1], tt[1]);
                }
                float q0 = m3(d2[0][0], d2[0][1], d2[1][0]);
                float q1 = m3(d2[1][1], d2[2][0], d2[2][1]);
                float q2 = m3(d2[3][0], d2[3][1], d2[4][0]);
                float q3 = m3(d2[4][1], d2[5][0], d2[5][1]);
                float q4 = m3(d2[6][0], d2[6][1], d2[7][0]);
                bv = fmaxf(m3(q0, q1, q2), m3(q3, q4, d2[7][1]));
            }
        }

        __syncthreads();
        // tail publish: m=1017..1023 (last in-loop batch covered through 1016)
        if (tid < 7) {
            const int mm = 1017 + tid;
            __hip_atomic_store(&gsel[(size_t)b * MM + mm],
                               (unsigned)(shist[mm] + 1),
                               __ATOMIC_RELAXED, __HIP_MEMORY_SCOPE_AGENT);
        }
        for (int i = tid; i < MM; i += 256) {
            float4 sp = spos[shist[i]];
            size_t o = (size_t)b * MM + i;
            pos_s[o * 3 + 0] = sp.x;
            pos_s[o * 3 + 1] = sp.y;
            pos_s[o * 3 + 2] = sp.z;
        }
        return;
    }

    // ===================== CONSUMER: radius + MLP =====================
    {
        const float4* s2 = (const float4*)W2;
        float4*       d2 = (float4*)sW2;
        for (int i = tid; i < 64 * 64 / 4; i += 256) d2[i] = s2[i];
        const float4* s3 = (const float4*)W3;
        float4*       d3 = (float4*)sW3;
        for (int i = tid; i < 64 * 128 / 4; i += 256) d3[i] = s3[i];
    }
    float w1c[6];
#pragma unroll
    for (int c = 0; c < 6; c++) w1c[c] = W1[c * 64 + lane];
    const float bb1  = b1[lane];
    const float bb2  = b2[lane];
    const float bb3a = b3[lane];
    const float bb3b = b3[64 + lane];
    __syncthreads();

    const int W = (blockIdx.x - BB) * 4 + wave;    // 0..991

    // collect this wave's queries and sort by m = q & 1023 (availability order)
    int myq[9]; int nq = 0;
#pragma unroll
    for (int k = 0; k < 9; k++) {
        int q = W + NWRK * k;
        if (q < BB * MM) myq[nq++] = q;
    }
    for (int i = 1; i < nq; i++) {                 // insertion sort (<=9 elems)
        int v = myq[i]; int j = i - 1;
        while (j >= 0 && (myq[j] & 1023) > (v & 1023)) { myq[j + 1] = myq[j]; j--; }
        myq[j + 1] = v;
    }

    for (int i = 0; i < nq; i++) {
        const int q = myq[i];

        // ---- wait for this single query (one address, deep sleep) ----
        unsigned v = 0u;
        int guard = 0;
        for (;;) {
            v = __hip_atomic_load(&gsel[q], __ATOMIC_RELAXED,
                                  __HIP_MEMORY_SCOPE_AGENT);
            if (v >= 1u && v <= (unsigned)NN) break;
            if (++guard > 6000) break;             // ~20ms bound: fail loudly
            __builtin_amdgcn_s_sleep(127);         // ~8128 cyc =~ 3.4us idle
        }
        if (v == 0u || v > (unsigned)NN) continue;

        // ---------- process query q ----------
        const int b  = q >> 10;
        const int fi = (int)v - 1;
        const float qx = pos[((size_t)b * NN + fi) * 3 + 0];
        const float qy = pos[((size_t)b * NN + fi) * 3 + 1];
        const float qz = pos[((size_t)b * NN + fi) * 3 + 2];

        // radius scan: first-16 by index within RSQ (identical semantics)
        if (lane < 16) nslot[wave][lane] = 0;
        const float* pb = pos + (size_t)b * NN * 3;
        int cnt = 0;
        for (int c = 0; c < NN / 64; c++) {
            int p = c * 64 + lane;
            float px = pb[p * 3 + 0], py = pb[p * 3 + 1], pz = pb[p * 3 + 2];
            float d2 = dist2_exact(qx, qy, qz, px, py, pz);
            bool val = (d2 <= RSQ);
            unsigned long long msk = __ballot(val);
            if (val) {
                int rank = __popcll(msk & ((1ull << lane) - 1ull));
                int slot = cnt + rank;
                if (slot < KK) nslot[wave][slot] = p;
            }
            cnt += __popcll(msk);
            if (cnt >= KK) break;
        }
        const int cnt16 = min(cnt, KK);

        const int4 n0 = *(const int4*)&nslot[wave][0];
        const int4 n1 = *(const int4*)&nslot[wave][4];
        const int4 n2 = *(const int4*)&nslot[wave][8];
        const int4 n3 = *(const int4*)&nslot[wave][12];
        const int nidx[16] = { n0.x, n0.y, n0.z, n0.w, n1.x, n1.y, n1.z, n1.w,
                               n2.x, n2.y, n2.z, n2.w, n3.x, n3.y, n3.z, n3.w };

        // layer 1
        float h[17];
        unsigned vmask = 1u << 16;
#pragma unroll
        for (int e = 0; e < 16; e++) {
            const int p = (e < cnt16) ? nidx[e] : 0;
            const int g = b * NN + p;
            if ((e < cnt16) && (g != q)) vmask |= (1u << e);
            const float f0 = x[(size_t)g * 3 + 0];
            const float f1 = x[(size_t)g * 3 + 1];
            const float f2 = x[(size_t)g * 3 + 2];
            const float f3 = pos[(size_t)g * 3 + 0] - qx;
            const float f4 = pos[(size_t)g * 3 + 1] - qy;
            const float f5 = pos[(size_t)g * 3 + 2] - qz;
            float t = bb1 + f0 * w1c[0] + f1 * w1c[1] + f2 * w1c[2]
                          + f3 * w1c[3] + f4 * w1c[4] + f5 * w1c[5];
            h[e] = fmaxf(t, 0.0f);
        }
        {   // added self-loop (PyG numeric quirk)
            const int g = q;
            const float f0 = x[(size_t)g * 3 + 0];
            const float f1 = x[(size_t)g * 3 + 1];
            const float f2 = x[(size_t)g * 3 + 2];
            const float f3 = pos[(size_t)g * 3 + 0] - qx;
            const float f4 = pos[(size_t)g * 3 + 1] - qy;
            const float f5 = pos[(size_t)g * 3 + 2] - qz;
            float t = bb1 + f0 * w1c[0] + f1 * w1c[1] + f2 * w1c[2]
                          + f3 * w1c[3] + f4 * w1c[4] + f5 * w1c[5];
            h[16] = fmaxf(t, 0.0f);
        }

        // layer 2
        float acc[17];
#pragma unroll
        for (int e = 0; e < 17; e++) acc[e] = bb2;
#pragma unroll 2
        for (int j = 0; j < 64; j++) {
            const float wj = sW2[j * 64 + lane];
#pragma unroll
            for (int e = 0; e < 17; e++) {
                const float hj = readlane_f(h[e], j);
                acc[e] = __builtin_fmaf(hj, wj, acc[e]);
            }
        }
#pragma unroll
        for (int e = 0; e < 17; e++) h[e] = fmaxf(acc[e], 0.0f);

        // layer 3
        float a0[17], a1[17];
#pragma unroll
        for (int e = 0; e < 17; e++) { a0[e] = bb3a; a1[e] = bb3b; }
#pragma unroll 2
        for (int j = 0; j < 64; j++) {
            const float wa = sW3[j * 128 + lane];
            const float wb = sW3[j * 128 + 64 + lane];
#pragma unroll
            for (int e = 0; e < 17; e++) {
                const float hj = readlane_f(h[e], j);
                a0[e] = __builtin_fmaf(hj, wa, a0[e]);
                a1[e] = __builtin_fmaf(hj, wb, a1[e]);
            }
        }

        // masked max
        float m0 = -INFINITY, m1 = -INFINITY;
#pragma unroll
        for (int e = 0; e < 17; e++) {
            const bool vv = (vmask >> e) & 1u;
            m0 = vv ? fmaxf(m0, a0[e]) : m0;
            m1 = vv ? fmaxf(m1, a1[e]) : m1;
        }
        out[(size_t)q * COUT + lane]      = m0;
        out[(size_t)q * COUT + 64 + lane] = m1;
    }
}

// ---------------------------------------------------------------------------
extern "C" void kernel_launch(void* const* d_in, const int* in_sizes, int n_in,
                              void* d_out, int out_size, void* d_ws, size_t ws_size,
                              hipStream_t stream) {
    const float* x   = (const float*)d_in[0];
    const float* pos = (const float*)d_in[1];
    // d_in[2] = batch (unused: layout is implicit)
    const float* W1 = (const float*)d_in[3];
    const float* b1 = (const float*)d_in[4];
    const float* W2 = (const float*)d_in[5];
    const float* b2 = (const float*)d_in[6];
    const float* W3 = (const float*)d_in[7];
    const float* b3 = (const float*)d_in[8];

    float* outF    = (float*)d_out;
    float* out     = outF;                                  // [B*M, 128]
    float* pos_s   = outF + (size_t)BB * MM * COUT;         // [B*M, 3]
    float* batch_s = pos_s + (size_t)BB * MM * 3;           // [B*M]

    unsigned* gsel = (unsigned*)d_ws;                       // [B*M] selection index+1

    hipMemsetAsync(gsel, 0, (size_t)BB * MM * sizeof(unsigned), stream);

    fused_kernel<<<256, 256, 0, stream>>>(x, pos, W1, b1, W2, b2, W3, b3,
                                          gsel, out, pos_s, batch_s);
}